// Round 12
// baseline (2328.624 us; speedup 1.0000x reference)
//
#include <hip/hip_runtime.h>

#define NN 100000
#define NE 3200000
#define NBUCK 782   // ceil(NN/128)
#define EPB 8192
#define NCB 391     // ceil(NE/EPB)
#define NTASK0 13531   // 640 prep + 391 hist + 12500 cvt
#define NSPMM 25000    // NN/4

typedef __attribute__((ext_vector_type(8))) short bf16x8;
typedef __attribute__((ext_vector_type(4))) float f32x4;
typedef __attribute__((ext_vector_type(2))) float f32x2;

struct MegaP {
  const float* x; const int* erow; const int* ecol; const float* ew;
  const float *W1,*b1,*g1,*be1,*m1,*v1;
  const float *W2,*b2,*g2,*be2,*m2,*v2;
  const float *W3,*b3;
  ushort *W1t,*W2t,*W3t;
  float *bp1,*bp2,*bp3;
  int *ghist,*bcnt,*bbase,*rp;
  unsigned* cw; int2* bdata;
  ushort* bufH; unsigned char *bufZ,*bufZ3;
  float* out;
  int* bar;   // [cnt, gen]
};

__device__ __forceinline__ ushort f2bf(float f) {
  unsigned u = __builtin_bit_cast(unsigned, f);
  u = (u + 0x7FFFu + ((u >> 16) & 1u)) >> 16;
  return (ushort)u;
}
__device__ __forceinline__ unsigned char f2fp8(float f) {
  return (unsigned char)(__builtin_amdgcn_cvt_pk_fp8_f32(f, 0.f, 0u, false) & 0xFFu);
}
__device__ __forceinline__ float pw2w(unsigned pw) {
  return __builtin_bit_cast(float, (pw & 0x7FFFu) << 16);
}
__device__ __forceinline__ void gl2lds16(const void* g, void* s) {
  __builtin_amdgcn_global_load_lds((const __attribute__((address_space(1))) void*)g,
                                   (__attribute__((address_space(3))) void*)s, 16, 0, 0);
}

// ---- device-scope grid barrier (requires all blocks co-resident) ----
__device__ __forceinline__ void gridbar(int* bar, int nblk) {
  __syncthreads();
  if (threadIdx.x == 0) {
    __threadfence();   // release: flush this XCD's dirty L2 (block's writes incl. all its threads)
    int* cnt = bar; int* gen = bar + 1;
    int g = __hip_atomic_load(gen, __ATOMIC_RELAXED, __HIP_MEMORY_SCOPE_AGENT);
    if (atomicAdd(cnt, 1) == nblk - 1) {
      __hip_atomic_store(cnt, 0, __ATOMIC_RELAXED, __HIP_MEMORY_SCOPE_AGENT);
      __hip_atomic_store(gen, g + 1, __ATOMIC_RELEASE, __HIP_MEMORY_SCOPE_AGENT);
    } else {
      while (__hip_atomic_load(gen, __ATOMIC_ACQUIRE, __HIP_MEMORY_SCOPE_AGENT) == g)
        __builtin_amdgcn_s_sleep(1);
    }
    __threadfence();   // acquire: invalidate stale L1/L2 before next phase's reads
  }
  __syncthreads();
}

// ================= phase task bodies (shared by mega + fallback) =================

__device__ __forceinline__ void prep_task(int task, const MegaP& P, int k) {
  if (task < 256) {
    int j = task;
    float s = P.g1[j] * rsqrtf(P.v1[j] + 1e-5f), t = P.be1[j] - P.m1[j] * s;
    if (k == 0) P.bp1[j] = P.b1[j] * s + t;
    P.W1t[(size_t)j * 256 + k] = f2bf(P.W1[(size_t)k * 256 + j] * s);
  } else if (task < 512) {
    int j = task - 256;
    float s = P.g2[j] * rsqrtf(P.v2[j] + 1e-5f), t = P.be2[j] - P.m2[j] * s;
    if (k == 0) P.bp2[j] = P.b2[j] * s + t;
    P.W2t[(size_t)j * 256 + k] = f2bf(P.W2[(size_t)k * 256 + j] * s);
  } else {
    int j = task - 512;  // 0..127, rows >= 64 zero-padded
    if (k == 0) P.bp3[j] = (j < 64) ? P.b3[j] : 0.f;
    P.W3t[(size_t)j * 256 + k] = f2bf((j < 64) ? P.W3[(size_t)k * 64 + j] : 0.f);
  }
}

__device__ __forceinline__ void cvt_task(int task, const float* __restrict__ x,
                                         ushort* __restrict__ xb, int k) {
  size_t i = ((size_t)task * 256 + k) * 8;
  float4 u = *(const float4*)(x + i);
  float4 v = *(const float4*)(x + i + 4);
  ushort4 r0; r0.x = f2bf(u.x); r0.y = f2bf(u.y); r0.z = f2bf(u.z); r0.w = f2bf(u.w);
  ushort4 r1; r1.x = f2bf(v.x); r1.y = f2bf(v.y); r1.z = f2bf(v.z); r1.w = f2bf(v.w);
  *(ushort4*)(xb + i) = r0;
  *(ushort4*)(xb + i + 4) = r1;
}

__device__ __forceinline__ void hist_task(int blk, const int* __restrict__ row,
                                          int* __restrict__ ghist, int* __restrict__ bcnt,
                                          int* h, int tid) {
  for (int i = tid; i < NBUCK; i += 256) h[i] = 0;
  __syncthreads();
  int lo = blk * EPB, hi = lo + EPB; if (hi > NE) hi = NE;
  for (int i = lo + tid * 4; i < hi; i += 1024) {
    int4 r = *(const int4*)(row + i);
    atomicAdd(&h[r.x >> 7], 1);
    atomicAdd(&h[r.y >> 7], 1);
    atomicAdd(&h[r.z >> 7], 1);
    atomicAdd(&h[r.w >> 7], 1);
  }
  __syncthreads();
  for (int i = tid; i < NBUCK; i += 256) {
    ghist[(size_t)i * NCB + blk] = h[i];
    if (h[i]) atomicAdd(&bcnt[i], h[i]);
  }
  __syncthreads();   // protect h before next task re-zeroes
}

__device__ __forceinline__ void scan_task(int b, int* __restrict__ ghist,
                                          const int* __restrict__ bcnt, int* __restrict__ bbase,
                                          int lane) {
  int acc = 0;
  for (int i = lane; i < b; i += 64) acc += bcnt[i];
#pragma unroll
  for (int o = 32; o > 0; o >>= 1) acc += __shfl_xor(acc, o, 64);
  int carry = acc;
  if (lane == 0) bbase[b] = carry;
#pragma unroll
  for (int r = 0; r < 7; ++r) {
    int idx = r * 64 + lane;
    int v = (idx < NCB) ? ghist[(size_t)b * NCB + idx] : 0;
    int s = v;
#pragma unroll
    for (int o = 1; o < 64; o <<= 1) { int t = __shfl_up(s, o, 64); if (lane >= o) s += t; }
    if (idx < NCB) ghist[(size_t)b * NCB + idx] = carry + s - v;
    carry += __shfl(s, 63, 64);
  }
}

__device__ __forceinline__ void place_task(int blk, const int* __restrict__ row,
                                           const int* __restrict__ col, const float* __restrict__ w,
                                           const int* __restrict__ ghist, int2* __restrict__ bdata,
                                           int* offs, int tid) {
  for (int i = tid; i < NBUCK; i += 256) offs[i] = ghist[(size_t)i * NCB + blk];
  __syncthreads();
  int lo = blk * EPB, hi = lo + EPB; if (hi > NE) hi = NE;
  for (int i = lo + tid * 4; i < hi; i += 1024) {
    int4 r = *(const int4*)(row + i);
    int4 c = *(const int4*)(col + i);
    float4 ww = *(const float4*)(w + i);
    int p;
    p = atomicAdd(&offs[r.x >> 7], 1); bdata[p] = make_int2(((r.x & 127) << 17) | c.x, __float_as_int(ww.x));
    p = atomicAdd(&offs[r.y >> 7], 1); bdata[p] = make_int2(((r.y & 127) << 17) | c.y, __float_as_int(ww.y));
    p = atomicAdd(&offs[r.z >> 7], 1); bdata[p] = make_int2(((r.z & 127) << 17) | c.z, __float_as_int(ww.z));
    p = atomicAdd(&offs[r.w >> 7], 1); bdata[p] = make_int2(((r.w & 127) << 17) | c.w, __float_as_int(ww.w));
  }
  __syncthreads();
}

__device__ __forceinline__ void bsort_task(int b, const int* __restrict__ bcnt,
                                           const int* __restrict__ bbase, const int2* __restrict__ bdata,
                                           unsigned* __restrict__ cw, int* __restrict__ rp,
                                           int* sc, int* lpos, int t) {
  int n = bcnt[b], base = bbase[b];
  if (t < 128) sc[t] = 0;
  __syncthreads();
  for (int i = t; i < n; i += 256) {
    int r = bdata[(size_t)base + i].x >> 17;
    atomicAdd(&sc[r], 1);
  }
  __syncthreads();
  for (int o = 1; o < 128; o <<= 1) {
    int v = (t < 128 && t >= o) ? sc[t - o] : 0;
    __syncthreads();
    if (t < 128) sc[t] += v;
    __syncthreads();
  }
  if (t < 128) {
    int excl = t ? sc[t - 1] : 0;
    lpos[t] = excl;
    int grow = b * 128 + t;
    if (grow <= NN) rp[grow] = base + excl;
  }
  __syncthreads();
  for (int i = t; i < n; i += 256) {
    int2 e = bdata[(size_t)base + i];
    int r = e.x >> 17;
    int p = atomicAdd(&lpos[r], 1);
    cw[base + p] = ((unsigned)(e.x & 0x1FFFF) << 15) | (f2bf(__int_as_float(e.y)) & 0x7FFFu);
  }
  __syncthreads();
}

// GEMM task: one block computes rows [bm*128,bm*128+128) x all ncst cols (bn halves serial).
__device__ __forceinline__ void gemm_task(const ushort* __restrict__ A, const ushort* __restrict__ Bt,
                                          const float* __restrict__ bp, unsigned char* __restrict__ C,
                                          int bm, int ldc, int ncst, char* sAb, char* sBb, int tid) {
  const int lane = tid & 63;
  const int wave = tid >> 6;
  const int wm = wave >> 1, wn = wave & 1;
  const int nbn = (ncst + 127) >> 7;
  for (int bn = 0; bn < nbn; ++bn) {
    f32x4 acc[4][4];
#pragma unroll
    for (int a = 0; a < 4; ++a)
#pragma unroll
      for (int b = 0; b < 4; ++b) acc[a][b] = (f32x4){0.f, 0.f, 0.f, 0.f};
    for (int kt = 0; kt < 4; ++kt) {
#pragma unroll
      for (int it = 0; it < 4; ++it) {
        int o = tid * 16 + it * 4096;
        int r = o >> 7, kb = o & 127;
        int ra = bm * 128 + r; if (ra >= NN) ra = NN - 1;
        gl2lds16((const char*)A + (size_t)ra * 512 + kt * 128 + kb, sAb + o);
        gl2lds16((const char*)Bt + (size_t)(bn * 128 + r) * 512 + kt * 128 + kb, sBb + o);
      }
      __syncthreads();
#pragma unroll
      for (int kk = 0; kk < 2; ++kk) {
        int kByte = kk * 64 + ((lane >> 4) << 4);
        bf16x8 af[4], bfr[4];
#pragma unroll
        for (int mi = 0; mi < 4; ++mi)
          af[mi] = *(const bf16x8*)(sAb + (wm * 64 + mi * 16 + (lane & 15)) * 128 + kByte);
#pragma unroll
        for (int ni = 0; ni < 4; ++ni)
          bfr[ni] = *(const bf16x8*)(sBb + (wn * 64 + ni * 16 + (lane & 15)) * 128 + kByte);
#pragma unroll
        for (int mi = 0; mi < 4; ++mi)
#pragma unroll
          for (int ni = 0; ni < 4; ++ni)
            acc[mi][ni] = __builtin_amdgcn_mfma_f32_16x16x32_bf16(af[mi], bfr[ni], acc[mi][ni], 0, 0, 0);
      }
      __syncthreads();
    }
    const int r0 = bm * 128 + wm * 64 + ((lane >> 4) << 2);
    const int c0 = bn * 128 + wn * 64 + (lane & 15);
#pragma unroll
    for (int ni = 0; ni < 4; ++ni) {
      int col = c0 + ni * 16;
      if (col < ncst) {
        float bpv = bp[col];
#pragma unroll
        for (int mi = 0; mi < 4; ++mi)
#pragma unroll
          for (int i = 0; i < 4; ++i) {
            int row = r0 + mi * 16 + i;
            if (row < NN) C[(size_t)row * ldc + col] = f2fp8(acc[mi][ni][i] + bpv);
          }
      }
    }
  }
}

__device__ __forceinline__ void gacc16(const unsigned* __restrict__ cw, int i, int rem,
                                       const char* __restrict__ Hb, f32x2& a01, f32x2& a23) {
  unsigned p[16]; unsigned g[16];
#pragma unroll
  for (int u = 0; u < 16; ++u) p[u] = cw[i + (u < rem ? u : 0)];
#pragma unroll
  for (int u = 0; u < 16; ++u) g[u] = *(const unsigned*)(Hb + ((size_t)(p[u] >> 15) << 8));
#pragma unroll
  for (int u = 0; u < 16; ++u) {
    float wf = (u < rem) ? pw2w(p[u]) : 0.f;
    f32x2 wv = {wf, wf};
    a01 += wv * __builtin_amdgcn_cvt_pk_f32_fp8(g[u], false);
    a23 += wv * __builtin_amdgcn_cvt_pk_f32_fp8(g[u], true);
  }
}

__device__ __forceinline__ void spmm256_node(int node, const int* __restrict__ rp,
                                             const unsigned* __restrict__ cw,
                                             const unsigned char* __restrict__ H,
                                             ushort* __restrict__ Y, int lane) {
  int s = __builtin_amdgcn_readfirstlane(rp[node]);
  int e = __builtin_amdgcn_readfirstlane(rp[node + 1]);
  f32x2 a01 = {0.f, 0.f}, a23 = {0.f, 0.f};
  const char* Hb = (const char*)H + (lane << 2);
  int i = s;
  for (; i + 16 <= e; i += 16) gacc16(cw, i, 16, Hb, a01, a23);
  int rem = e - i;
  if (rem) gacc16(cw, i, rem, Hb, a01, a23);
  ushort4 o;
  o.x = f2bf(fmaxf(a01.x, 0.f)); o.y = f2bf(fmaxf(a01.y, 0.f));
  o.z = f2bf(fmaxf(a23.x, 0.f)); o.w = f2bf(fmaxf(a23.y, 0.f));
  *(ushort4*)(Y + (size_t)node * 256 + (lane << 2)) = o;
}

__device__ __forceinline__ void gacc64(const unsigned* __restrict__ cw, int i, int rem,
                                       const unsigned char* __restrict__ H, int word, int shift, float& a) {
  unsigned p[16]; unsigned g[16];
#pragma unroll
  for (int u = 0; u < 16; ++u) p[u] = cw[i + (u < rem ? u : 0)];
#pragma unroll
  for (int u = 0; u < 16; ++u)
    g[u] = *(const unsigned*)(H + ((size_t)(p[u] >> 15) << 6) + word);
#pragma unroll
  for (int u = 0; u < 16; ++u) {
    float h = __builtin_amdgcn_cvt_f32_fp8(g[u] >> shift, 0);
    a += ((u < rem) ? pw2w(p[u]) : 0.f) * h;
  }
}

__device__ __forceinline__ void spmm64_node(int node, const int* __restrict__ rp,
                                            const unsigned* __restrict__ cw,
                                            const unsigned char* __restrict__ H,
                                            float* __restrict__ out, int lane) {
  int s = __builtin_amdgcn_readfirstlane(rp[node]);
  int e = __builtin_amdgcn_readfirstlane(rp[node + 1]);
  int word = (lane >> 2) << 2;
  int shift = (lane & 3) << 3;
  float a = 0.f;
  int i = s;
  for (; i + 16 <= e; i += 16) gacc64(cw, i, 16, H, word, shift, a);
  int rem = e - i;
  if (rem) gacc64(cw, i, rem, H, word, shift, a);
  float mx = a;
#pragma unroll
  for (int o = 32; o > 0; o >>= 1) mx = fmaxf(mx, __shfl_xor(mx, o, 64));
  float ex = expf(a - mx);
  float sum = ex;
#pragma unroll
  for (int o = 32; o > 0; o >>= 1) sum += __shfl_xor(sum, o, 64);
  out[(size_t)node * 64 + lane] = (a - mx) - logf(sum);
}

// ================= persistent mega-kernel =================
__global__ __launch_bounds__(256, 4) void k_mega(MegaP P) {
  __shared__ int h[NBUCK];
  __shared__ ushort sA[128 * 64];
  __shared__ ushort sB[128 * 64];
  const int tid = threadIdx.x;
  const int lane = tid & 63;
  const int wave = tid >> 6;
  const int nblk = gridDim.x;

  // P0: weight prep | edge histogram | x->bf16
  for (int task = blockIdx.x; task < NTASK0; task += nblk) {
    if (task < 640) prep_task(task, P, tid);
    else if (task < 1031) hist_task(task - 640, P.erow, P.ghist, P.bcnt, h, tid);
    else cvt_task(task - 1031, P.x, P.bufH, tid);
  }
  gridbar(P.bar, nblk);
  // P1: per-bucket offset scan (wave tasks)
  for (int b = blockIdx.x * 4 + wave; b < NBUCK; b += nblk * 4)
    scan_task(b, P.ghist, P.bcnt, P.bbase, lane);
  gridbar(P.bar, nblk);
  // P2: edge placement
  for (int task = blockIdx.x; task < NCB; task += nblk)
    place_task(task, P.erow, P.ecol, P.ew, P.ghist, P.bdata, h, tid);
  gridbar(P.bar, nblk);
  // P3: row sort -> rp + packed cw
  for (int task = blockIdx.x; task < NBUCK; task += nblk)
    bsort_task(task, P.bcnt, P.bbase, P.bdata, P.cw, P.rp, h, h + 128, tid);
  gridbar(P.bar, nblk);
  // P4: z1 = x @ W1' + b1'
  for (int task = blockIdx.x; task < 782; task += nblk)
    gemm_task(P.bufH, P.W1t, P.bp1, P.bufZ, task, 256, 256, (char*)sA, (char*)sB, tid);
  gridbar(P.bar, nblk);
  // P5: h1 = relu(P @ z1)
  for (int task = blockIdx.x; task < NSPMM; task += nblk)
    spmm256_node(task * 4 + wave, P.rp, P.cw, P.bufZ, P.bufH, lane);
  gridbar(P.bar, nblk);
  // P6: z2 = h1 @ W2' + b2'
  for (int task = blockIdx.x; task < 782; task += nblk)
    gemm_task(P.bufH, P.W2t, P.bp2, P.bufZ, task, 256, 256, (char*)sA, (char*)sB, tid);
  gridbar(P.bar, nblk);
  // P7: h2 = relu(P @ z2)
  for (int task = blockIdx.x; task < NSPMM; task += nblk)
    spmm256_node(task * 4 + wave, P.rp, P.cw, P.bufZ, P.bufH, lane);
  gridbar(P.bar, nblk);
  // P8: z3 = h2 @ W3 + b3
  for (int task = blockIdx.x; task < 782; task += nblk)
    gemm_task(P.bufH, P.W3t, P.bp3, P.bufZ3, task, 64, 64, (char*)sA, (char*)sB, tid);
  gridbar(P.bar, nblk);
  // P9: out = log_softmax(P @ z3)
  for (int task = blockIdx.x; task < NSPMM; task += nblk)
    spmm64_node(task * 4 + wave, P.rp, P.cw, P.bufZ3, P.out, lane);
}

// ================= fallback wrappers (multi-kernel pipeline) =================
__global__ __launch_bounds__(256) void k_pcw(MegaP P) {
  __shared__ int h[NBUCK];
  int bid = blockIdx.x, tid = threadIdx.x;
  if (bid < 640) prep_task(bid, P, tid);
  else if (bid < 1031) hist_task(bid - 640, P.erow, P.ghist, P.bcnt, h, tid);
  else cvt_task(bid - 1031, P.x, P.bufH, tid);
}
__global__ __launch_bounds__(64) void k_scanw(MegaP P) {
  scan_task(blockIdx.x, P.ghist, P.bcnt, P.bbase, threadIdx.x);
}
__global__ __launch_bounds__(256) void k_placew(MegaP P) {
  __shared__ int h[NBUCK];
  place_task(blockIdx.x, P.erow, P.ecol, P.ew, P.ghist, P.bdata, h, threadIdx.x);
}
__global__ __launch_bounds__(256) void k_bsortw(MegaP P) {
  __shared__ int sc[128], lpos[128];
  bsort_task(blockIdx.x, P.bcnt, P.bbase, P.bdata, P.cw, P.rp, sc, lpos, threadIdx.x);
}
__global__ __launch_bounds__(256) void k_gemmw(const ushort* A, const ushort* Bt, const float* bp,
                                               unsigned char* C, int ldc, int ncst) {
  __shared__ ushort sA[128 * 64];
  __shared__ ushort sB[128 * 64];
  gemm_task(A, Bt, bp, C, blockIdx.x, ldc, ncst, (char*)sA, (char*)sB, threadIdx.x);
}
__global__ __launch_bounds__(256) void k_spmm256w(const int* rp, const unsigned* cw,
                                                  const unsigned char* H, ushort* Y) {
  spmm256_node(blockIdx.x * 4 + (threadIdx.x >> 6), rp, cw, H, Y, threadIdx.x & 63);
}
__global__ __launch_bounds__(256) void k_spmm64w(const int* rp, const unsigned* cw,
                                                  const unsigned char* H, float* out) {
  spmm64_node(blockIdx.x * 4 + (threadIdx.x >> 6), rp, cw, H, out, threadIdx.x & 63);
}

extern "C" void kernel_launch(void* const* d_in, const int* in_sizes, int n_in,
                              void* d_out, int out_size, void* d_ws, size_t ws_size,
                              hipStream_t stream) {
  MegaP P;
  P.x   = (const float*)d_in[0];
  P.erow = (const int*)d_in[1];
  P.ecol = (const int*)d_in[2];
  P.ew  = (const float*)d_in[3];
  P.W1 = (const float*)d_in[4];  P.b1 = (const float*)d_in[5];
  P.g1 = (const float*)d_in[6];  P.be1 = (const float*)d_in[7];
  P.m1 = (const float*)d_in[8];  P.v1 = (const float*)d_in[9];
  P.W2 = (const float*)d_in[10]; P.b2 = (const float*)d_in[11];
  P.g2 = (const float*)d_in[12]; P.be2 = (const float*)d_in[13];
  P.m2 = (const float*)d_in[14]; P.v2 = (const float*)d_in[15];
  P.W3 = (const float*)d_in[16]; P.b3 = (const float*)d_in[17];
  P.out = (float*)d_out;

  char* ws = (char*)d_ws;
  size_t off = 0;
  auto carve = [&](size_t bytes) -> void* {
    void* p = ws + off;
    off += (bytes + 511) & ~(size_t)511;
    return p;
  };
  P.bar   = (int*)carve(8);
  P.bcnt  = (int*)carve((size_t)NBUCK * 4);
  P.bbase = (int*)carve((size_t)NBUCK * 4);
  P.ghist = (int*)carve((size_t)NBUCK * NCB * 4);
  P.rp    = (int*)carve((size_t)(NBUCK * 128 + 1) * 4);
  P.cw    = (unsigned*)carve((size_t)NE * 4);
  P.bdata = (int2*)carve((size_t)NE * 8);
  P.W1t   = (ushort*)carve(256 * 256 * 2);
  P.W2t   = (ushort*)carve(256 * 256 * 2);
  P.W3t   = (ushort*)carve(128 * 256 * 2);
  P.bp1   = (float*)carve(256 * 4);
  P.bp2   = (float*)carve(256 * 4);
  P.bp3   = (float*)carve(128 * 4);
  P.bufH  = (ushort*)carve((size_t)NN * 256 * 2);
  P.bufZ  = (unsigned char*)carve((size_t)NN * 256);
  P.bufZ3 = (unsigned char*)carve((size_t)NN * 64);
  if (off > ws_size) return;

  hipMemsetAsync(P.bar, 0, 8, stream);
  hipMemsetAsync(P.bcnt, 0, (size_t)NBUCK * 4, stream);

  int nb = 0;
  hipError_t e = hipOccupancyMaxActiveBlocksPerMultiprocessor(&nb, (const void*)k_mega, 256, 0);
  if (e == hipSuccess && nb > 0) {
    int grid = nb * 256;               // 256 CUs on MI355X; grid <= co-resident capacity
    if (grid > 2048) grid = 2048;
    k_mega<<<grid, 256, 0, stream>>>(P);
  } else {
    // fallback: multi-kernel pipeline (identical task bodies)
    k_pcw<<<NTASK0, 256, 0, stream>>>(P);
    k_scanw<<<NBUCK, 64, 0, stream>>>(P);
    k_placew<<<NCB, 256, 0, stream>>>(P);
    k_bsortw<<<NBUCK, 256, 0, stream>>>(P);
    k_gemmw<<<782, 256, 0, stream>>>(P.bufH, P.W1t, P.bp1, P.bufZ, 256, 256);
    k_spmm256w<<<NSPMM, 256, 0, stream>>>(P.rp, P.cw, P.bufZ, P.bufH);
    k_gemmw<<<782, 256, 0, stream>>>(P.bufH, P.W2t, P.bp2, P.bufZ, 256, 256);
    k_spmm256w<<<NSPMM, 256, 0, stream>>>(P.rp, P.cw, P.bufZ, P.bufH);
    k_gemmw<<<782, 256, 0, stream>>>(P.bufH, P.W3t, P.bp3, P.bufZ3, 64, 64);
    k_spmm64w<<<NSPMM, 256, 0, stream>>>(P.rp, P.cw, P.bufZ3, P.out);
  }
}

// Round 13
// 506.716 us; speedup vs baseline: 4.5955x; 4.5955x over previous
//
#include <hip/hip_runtime.h>

#define NN 100000
#define NE 3200000
#define NBUCK 782   // ceil(NN/128)
#define EPB 8192
#define NCB 391     // ceil(NE/EPB)

typedef __attribute__((ext_vector_type(8))) short bf16x8;
typedef __attribute__((ext_vector_type(4))) float f32x4;
typedef __attribute__((ext_vector_type(2))) float f32x2;

__device__ __forceinline__ ushort f2bf(float f) {
  unsigned u = __builtin_bit_cast(unsigned, f);
  u = (u + 0x7FFFu + ((u >> 16) & 1u)) >> 16;
  return (ushort)u;
}
// f32 -> fp8 e4m3 (OCP), single byte
__device__ __forceinline__ unsigned char f2fp8(float f) {
  return (unsigned char)(__builtin_amdgcn_cvt_pk_fp8_f32(f, 0.f, 0u, false) & 0xFFu);
}
// packed edge: [31:15]=col (17b), [14:0]=bf16(w) sans sign (w >= 0)
__device__ __forceinline__ float pw2w(unsigned pw) {
  return __builtin_bit_cast(float, (pw & 0x7FFFu) << 16);
}
__device__ __forceinline__ void gl2lds16(const void* g, void* s) {
  __builtin_amdgcn_global_load_lds((const __attribute__((address_space(1))) void*)g,
                                   (__attribute__((address_space(3))) void*)s, 16, 0, 0);
}

// ---- merged: weight prep (blocks 0..639) | per-block edge histogram (blocks 640..1030) ----
__global__ __launch_bounds__(256) void k_pc(
    const float* __restrict__ W1, const float* __restrict__ b1, const float* __restrict__ g1,
    const float* __restrict__ be1, const float* __restrict__ m1, const float* __restrict__ v1,
    const float* __restrict__ W2, const float* __restrict__ b2, const float* __restrict__ g2,
    const float* __restrict__ be2, const float* __restrict__ m2, const float* __restrict__ v2,
    const float* __restrict__ W3, const float* __restrict__ b3,
    ushort* __restrict__ W1t, ushort* __restrict__ W2t, ushort* __restrict__ W3t,
    float* __restrict__ bp1, float* __restrict__ bp2, float* __restrict__ bp3,
    const int* __restrict__ row, int* __restrict__ ghist, int* __restrict__ bcnt) {
  __shared__ int h[NBUCK];
  int bid = blockIdx.x, k = threadIdx.x;
  if (bid < 640) {
    if (bid < 256) {
      int j = bid;
      float s = g1[j] * rsqrtf(v1[j] + 1e-5f), t = be1[j] - m1[j] * s;
      if (k == 0) bp1[j] = b1[j] * s + t;
      W1t[(size_t)j * 256 + k] = f2bf(W1[(size_t)k * 256 + j] * s);
    } else if (bid < 512) {
      int j = bid - 256;
      float s = g2[j] * rsqrtf(v2[j] + 1e-5f), t = be2[j] - m2[j] * s;
      if (k == 0) bp2[j] = b2[j] * s + t;
      W2t[(size_t)j * 256 + k] = f2bf(W2[(size_t)k * 256 + j] * s);
    } else {
      int j = bid - 512;  // 0..127, rows >= 64 zero-padded
      if (k == 0) bp3[j] = (j < 64) ? b3[j] : 0.f;
      W3t[(size_t)j * 256 + k] = f2bf((j < 64) ? W3[(size_t)k * 64 + j] : 0.f);
    }
    return;
  }
  // ---- edge histogram ----
  int blk = bid - 640;
  for (int i = k; i < NBUCK; i += 256) h[i] = 0;
  __syncthreads();
  int lo = blk * EPB, hi = lo + EPB; if (hi > NE) hi = NE;
  for (int i = lo + k * 4; i < hi; i += 1024) {
    int4 r = *(const int4*)(row + i);
    atomicAdd(&h[r.x >> 7], 1);
    atomicAdd(&h[r.y >> 7], 1);
    atomicAdd(&h[r.z >> 7], 1);
    atomicAdd(&h[r.w >> 7], 1);
  }
  __syncthreads();
  for (int i = k; i < NBUCK; i += 256) {
    ghist[(size_t)i * NCB + blk] = h[i];
    if (h[i]) atomicAdd(&bcnt[i], h[i]);
  }
}

// ---------------- per-bucket scan (computes own base from bcnt; writes bbase) ----------------
__global__ __launch_bounds__(64) void k_scan3(int* __restrict__ ghist, const int* __restrict__ bcnt,
                                              int* __restrict__ bbase) {
  int b = blockIdx.x, lane = threadIdx.x;
  int acc = 0;
  for (int i = lane; i < b; i += 64) acc += bcnt[i];
#pragma unroll
  for (int o = 32; o > 0; o >>= 1) acc += __shfl_xor(acc, o, 64);
  int carry = acc;   // bucket base (uniform across lanes)
  if (lane == 0) bbase[b] = carry;
#pragma unroll
  for (int r = 0; r < 7; ++r) {     // 7*64 = 448 >= 391
    int idx = r * 64 + lane;
    int v = (idx < NCB) ? ghist[(size_t)b * NCB + idx] : 0;
    int s = v;
#pragma unroll
    for (int o = 1; o < 64; o <<= 1) { int t = __shfl_up(s, o, 64); if (lane >= o) s += t; }
    if (idx < NCB) ghist[(size_t)b * NCB + idx] = carry + s - v;
    carry += __shfl(s, 63, 64);
  }
}

// ---- merged: GEMM1 (blocks 0..781, fp32 A, both bn halves) | edge placement (782..1172) ----
__global__ __launch_bounds__(256) void k_pg1(const float* __restrict__ A, const ushort* __restrict__ Bt,
                                             const float* __restrict__ bp, unsigned char* __restrict__ C,
                                             const int* __restrict__ row, const int* __restrict__ col,
                                             const float* __restrict__ w, const int* __restrict__ ghist,
                                             int2* __restrict__ bdata) {
  __shared__ char smem[32768];
  int bid = blockIdx.x;
  const int tid = threadIdx.x;
  if (bid >= 782) {
    // ---- edge placement ----
    int* offs = (int*)smem;
    int blk = bid - 782;
    for (int i = tid; i < NBUCK; i += 256) offs[i] = ghist[(size_t)i * NCB + blk];
    __syncthreads();
    int lo = blk * EPB, hi = lo + EPB; if (hi > NE) hi = NE;
    for (int i = lo + tid * 4; i < hi; i += 1024) {
      int4 r = *(const int4*)(row + i);
      int4 c = *(const int4*)(col + i);
      float4 ww = *(const float4*)(w + i);
      int p;
      p = atomicAdd(&offs[r.x >> 7], 1); bdata[p] = make_int2(((r.x & 127) << 17) | c.x, __float_as_int(ww.x));
      p = atomicAdd(&offs[r.y >> 7], 1); bdata[p] = make_int2(((r.y & 127) << 17) | c.y, __float_as_int(ww.y));
      p = atomicAdd(&offs[r.z >> 7], 1); bdata[p] = make_int2(((r.z & 127) << 17) | c.z, __float_as_int(ww.z));
      p = atomicAdd(&offs[r.w >> 7], 1); bdata[p] = make_int2(((r.w & 127) << 17) | c.w, __float_as_int(ww.w));
    }
    return;
  }
  // ---- GEMM1: C = x[fp32] @ W1t^T + bias, fp8 out; one block = 128 rows x both 128-col halves ----
  char* sAb = smem;
  char* sBb = smem + 16384;
  const int lane = tid & 63;
  const int wave = tid >> 6;
  const int wm = wave >> 1, wn = wave & 1;
  const int bm = bid;

  for (int bn = 0; bn < 2; ++bn) {
    f32x4 acc[4][4];
#pragma unroll
    for (int a = 0; a < 4; ++a)
#pragma unroll
      for (int b = 0; b < 4; ++b) acc[a][b] = (f32x4){0.f, 0.f, 0.f, 0.f};

    for (int kt = 0; kt < 4; ++kt) {
      // A: fp32 load -> bf16 -> single 16B LDS store per thread (conflict-free)
#pragma unroll
      for (int it = 0; it < 4; ++it) {
        int r = it * 32 + (tid >> 3);        // 0..127
        int colx = (tid & 7) * 8;            // 0..56
        int ra = bm * 128 + r; if (ra >= NN) ra = NN - 1;
        const float* src = A + (size_t)ra * 256 + kt * 64 + colx;
        float4 u = *(const float4*)src;
        float4 v = *(const float4*)(src + 4);
        bf16x8 t;
        t[0] = (short)f2bf(u.x); t[1] = (short)f2bf(u.y);
        t[2] = (short)f2bf(u.z); t[3] = (short)f2bf(u.w);
        t[4] = (short)f2bf(v.x); t[5] = (short)f2bf(v.y);
        t[6] = (short)f2bf(v.z); t[7] = (short)f2bf(v.w);
        *(bf16x8*)(sAb + r * 128 + colx * 2) = t;
      }
      // B: direct global->LDS
#pragma unroll
      for (int it = 0; it < 4; ++it) {
        int o = tid * 16 + it * 4096;
        int r = o >> 7, kb = o & 127;
        gl2lds16((const char*)Bt + (size_t)(bn * 128 + r) * 512 + kt * 128 + kb, sBb + o);
      }
      __syncthreads();
#pragma unroll
      for (int kk = 0; kk < 2; ++kk) {
        int kByte = kk * 64 + ((lane >> 4) << 4);
        bf16x8 af[4], bfr[4];
#pragma unroll
        for (int mi = 0; mi < 4; ++mi)
          af[mi] = *(const bf16x8*)(sAb + (wm * 64 + mi * 16 + (lane & 15)) * 128 + kByte);
#pragma unroll
        for (int ni = 0; ni < 4; ++ni)
          bfr[ni] = *(const bf16x8*)(sBb + (wn * 64 + ni * 16 + (lane & 15)) * 128 + kByte);
#pragma unroll
        for (int mi = 0; mi < 4; ++mi)
#pragma unroll
          for (int ni = 0; ni < 4; ++ni)
            acc[mi][ni] = __builtin_amdgcn_mfma_f32_16x16x32_bf16(af[mi], bfr[ni], acc[mi][ni], 0, 0, 0);
      }
      __syncthreads();
    }

    const int r0 = bm * 128 + wm * 64 + ((lane >> 4) << 2);
    const int c0 = bn * 128 + wn * 64 + (lane & 15);
#pragma unroll
    for (int ni = 0; ni < 4; ++ni) {
      int col2 = c0 + ni * 16;
      float bpv = bp[col2];
#pragma unroll
      for (int mi = 0; mi < 4; ++mi)
#pragma unroll
        for (int i = 0; i < 4; ++i) {
          int r = r0 + mi * 16 + i;
          if (r < NN) C[(size_t)r * 256 + col2] = f2fp8(acc[mi][ni][i] + bpv);
        }
    }
  }
}

// ---------------- per-bucket row sort -> rp + packed cw ----------------
__global__ __launch_bounds__(256) void k_bsort(const int* __restrict__ bcnt, const int* __restrict__ bbase,
                                               const int2* __restrict__ bdata, unsigned* __restrict__ cw,
                                               int* __restrict__ rp) {
  __shared__ int sc[128], lpos[128];
  int b = blockIdx.x, t = threadIdx.x;
  int n = bcnt[b], base = bbase[b];
  if (t < 128) sc[t] = 0;
  __syncthreads();
  for (int i = t; i < n; i += 256) {
    int r = bdata[(size_t)base + i].x >> 17;
    atomicAdd(&sc[r], 1);
  }
  __syncthreads();
  for (int o = 1; o < 128; o <<= 1) {
    int v = (t < 128 && t >= o) ? sc[t - o] : 0;
    __syncthreads();
    if (t < 128) sc[t] += v;
    __syncthreads();
  }
  if (t < 128) {
    int excl = t ? sc[t - 1] : 0;
    lpos[t] = excl;
    int grow = b * 128 + t;
    if (grow <= NN) rp[grow] = base + excl;
  }
  __syncthreads();
  for (int i = t; i < n; i += 256) {
    int2 e = bdata[(size_t)base + i];
    int r = e.x >> 17;
    int p = atomicAdd(&lpos[r], 1);
    cw[base + p] = ((unsigned)(e.x & 0x1FFFF) << 15) | (f2bf(__int_as_float(e.y)) & 0x7FFFu);
  }
}

// ---------------- bf16 MFMA GEMM: C[M x ncst] = A[M x 256] @ Wt^T + bias, fp8 out ----------------
__global__ __launch_bounds__(256) void k_gemm(const ushort* __restrict__ A, const ushort* __restrict__ Bt,
                                              const float* __restrict__ bp, unsigned char* __restrict__ C,
                                              int M, int ldc, int ncst) {
  __shared__ ushort sA[128 * 64];
  __shared__ ushort sB[128 * 64];
  const int tid = threadIdx.x;
  const int lane = tid & 63;
  const int wave = tid >> 6;
  const int wm = wave >> 1, wn = wave & 1;
  const int bm = blockIdx.x, bn = blockIdx.y;

  f32x4 acc[4][4];
#pragma unroll
  for (int a = 0; a < 4; ++a)
#pragma unroll
    for (int b = 0; b < 4; ++b) acc[a][b] = (f32x4){0.f, 0.f, 0.f, 0.f};

  const char* Ab = (const char*)A;
  const char* Bb = (const char*)Bt;
  char* sAb = (char*)sA;
  char* sBb = (char*)sB;

  for (int kt = 0; kt < 4; ++kt) {
#pragma unroll
    for (int it = 0; it < 4; ++it) {
      int o = tid * 16 + it * 4096;
      int r = o >> 7, kb = o & 127;
      int ra = bm * 128 + r; if (ra >= M) ra = M - 1;
      gl2lds16(Ab + (size_t)ra * 512 + kt * 128 + kb, sAb + o);
      gl2lds16(Bb + (size_t)(bn * 128 + r) * 512 + kt * 128 + kb, sBb + o);
    }
    __syncthreads();
#pragma unroll
    for (int kk = 0; kk < 2; ++kk) {
      int kByte = kk * 64 + ((lane >> 4) << 4);
      bf16x8 af[4], bfr[4];
#pragma unroll
      for (int mi = 0; mi < 4; ++mi)
        af[mi] = *(const bf16x8*)(sAb + (wm * 64 + mi * 16 + (lane & 15)) * 128 + kByte);
#pragma unroll
      for (int ni = 0; ni < 4; ++ni)
        bfr[ni] = *(const bf16x8*)(sBb + (wn * 64 + ni * 16 + (lane & 15)) * 128 + kByte);
#pragma unroll
      for (int mi = 0; mi < 4; ++mi)
#pragma unroll
        for (int ni = 0; ni < 4; ++ni)
          acc[mi][ni] = __builtin_amdgcn_mfma_f32_16x16x32_bf16(af[mi], bfr[ni], acc[mi][ni], 0, 0, 0);
    }
    __syncthreads();
  }

  const int r0 = bm * 128 + wm * 64 + ((lane >> 4) << 2);
  const int c0 = bn * 128 + wn * 64 + (lane & 15);
#pragma unroll
  for (int ni = 0; ni < 4; ++ni) {
    int col = c0 + ni * 16;
    if (col >= ncst) continue;
    float bpv = bp[col];
#pragma unroll
    for (int mi = 0; mi < 4; ++mi)
#pragma unroll
      for (int i = 0; i < 4; ++i) {
        int row = r0 + mi * 16 + i;
        if (row < M) C[(size_t)row * ldc + col] = f2fp8(acc[mi][ni][i] + bpv);
      }
  }
}

// gather-accumulate one batch of up to 16 edges (fp8 source, packed 4B cw)
__device__ __forceinline__ void gacc16(const unsigned* __restrict__ cw, int i, int rem,
                                       const char* __restrict__ Hb, f32x2& a01, f32x2& a23) {
  unsigned p[16]; unsigned g[16];
#pragma unroll
  for (int u = 0; u < 16; ++u) p[u] = cw[i + (u < rem ? u : 0)];
#pragma unroll
  for (int u = 0; u < 16; ++u) g[u] = *(const unsigned*)(Hb + ((size_t)(p[u] >> 15) << 8));
#pragma unroll
  for (int u = 0; u < 16; ++u) {
    float wf = (u < rem) ? pw2w(p[u]) : 0.f;
    f32x2 wv = {wf, wf};
    a01 += wv * __builtin_amdgcn_cvt_pk_f32_fp8(g[u], false);
    a23 += wv * __builtin_amdgcn_cvt_pk_f32_fp8(g[u], true);
  }
}

// ---------------- SpMM 256-dim: Y[i,:] = relu(sum w_e * H[col_e,:]), fp8 in, bf16 out ----------------
__global__ __launch_bounds__(256) void k_spmm256(const int* __restrict__ rp, const unsigned* __restrict__ cw,
                                                 const unsigned char* __restrict__ H, ushort* __restrict__ Y) {
  int node = blockIdx.x * 4 + (threadIdx.x >> 6);
  int lane = threadIdx.x & 63;
  int s = __builtin_amdgcn_readfirstlane(rp[node]);
  int e = __builtin_amdgcn_readfirstlane(rp[node + 1]);
  f32x2 a01 = {0.f, 0.f}, a23 = {0.f, 0.f};
  const char* Hb = (const char*)H + (lane << 2);   // 4 fp8 dims per lane
  int i = s;
  for (; i + 16 <= e; i += 16) gacc16(cw, i, 16, Hb, a01, a23);
  int rem = e - i;
  if (rem) gacc16(cw, i, rem, Hb, a01, a23);
  ushort4 o;
  o.x = f2bf(fmaxf(a01.x, 0.f)); o.y = f2bf(fmaxf(a01.y, 0.f));
  o.z = f2bf(fmaxf(a23.x, 0.f)); o.w = f2bf(fmaxf(a23.y, 0.f));
  *(ushort4*)(Y + (size_t)node * 256 + (lane << 2)) = o;
}

// ---------------- SpMM 64-dim + fused log_softmax, fp8 in, fp32 out ----------------
__device__ __forceinline__ void gacc64(const unsigned* __restrict__ cw, int i, int rem,
                                       const unsigned char* __restrict__ H, int word, int shift, float& a) {
  unsigned p[16]; unsigned g[16];
#pragma unroll
  for (int u = 0; u < 16; ++u) p[u] = cw[i + (u < rem ? u : 0)];
#pragma unroll
  for (int u = 0; u < 16; ++u)
    g[u] = *(const unsigned*)(H + ((size_t)(p[u] >> 15) << 6) + word);
#pragma unroll
  for (int u = 0; u < 16; ++u) {
    float h = __builtin_amdgcn_cvt_f32_fp8(g[u] >> shift, 0);
    a += ((u < rem) ? pw2w(p[u]) : 0.f) * h;
  }
}

__global__ __launch_bounds__(256) void k_spmm64(const int* __restrict__ rp, const unsigned* __restrict__ cw,
                                                const unsigned char* __restrict__ H, float* __restrict__ out) {
  int node = blockIdx.x * 4 + (threadIdx.x >> 6);
  int lane = threadIdx.x & 63;
  int s = __builtin_amdgcn_readfirstlane(rp[node]);
  int e = __builtin_amdgcn_readfirstlane(rp[node + 1]);
  int word = (lane >> 2) << 2;      // dword offset within 64B row
  int shift = (lane & 3) << 3;      // byte within dword
  float a = 0.f;
  int i = s;
  for (; i + 16 <= e; i += 16) gacc64(cw, i, 16, H, word, shift, a);
  int rem = e - i;
  if (rem) gacc64(cw, i, rem, H, word, shift, a);
  float mx = a;
#pragma unroll
  for (int o = 32; o > 0; o >>= 1) mx = fmaxf(mx, __shfl_xor(mx, o, 64));
  float ex = expf(a - mx);
  float sum = ex;
#pragma unroll
  for (int o = 32; o > 0; o >>= 1) sum += __shfl_xor(sum, o, 64);
  out[(size_t)node * 64 + lane] = (a - mx) - logf(sum);
}

extern "C" void kernel_launch(void* const* d_in, const int* in_sizes, int n_in,
                              void* d_out, int out_size, void* d_ws, size_t ws_size,
                              hipStream_t stream) {
  const float* x   = (const float*)d_in[0];
  const int* erow  = (const int*)d_in[1];
  const int* ecol  = (const int*)d_in[2];
  const float* ew  = (const float*)d_in[3];
  const float* W1  = (const float*)d_in[4];
  const float* b1  = (const float*)d_in[5];
  const float* g1  = (const float*)d_in[6];
  const float* be1 = (const float*)d_in[7];
  const float* m1  = (const float*)d_in[8];
  const float* v1  = (const float*)d_in[9];
  const float* W2  = (const float*)d_in[10];
  const float* b2  = (const float*)d_in[11];
  const float* g2  = (const float*)d_in[12];
  const float* be2 = (const float*)d_in[13];
  const float* m2  = (const float*)d_in[14];
  const float* v2  = (const float*)d_in[15];
  const float* W3  = (const float*)d_in[16];
  const float* b3  = (const float*)d_in[17];

  char* ws = (char*)d_ws;
  size_t off = 0;
  auto carve = [&](size_t bytes) -> void* {
    void* p = ws + off;
    off += (bytes + 511) & ~(size_t)511;
    return p;
  };
  int* bcnt    = (int*)carve((size_t)NBUCK * 4);
  int* bbase   = (int*)carve((size_t)NBUCK * 4);
  int* ghist   = (int*)carve((size_t)NBUCK * NCB * 4);
  int* rp      = (int*)carve((size_t)(NBUCK * 128 + 1) * 4);
  unsigned* cw = (unsigned*)carve((size_t)NE * 4);
  ushort* W1t  = (ushort*)carve(256 * 256 * 2);
  ushort* W2t  = (ushort*)carve(256 * 256 * 2);
  ushort* W3t  = (ushort*)carve(128 * 256 * 2);
  float* bp1   = (float*)carve(256 * 4);
  float* bp2   = (float*)carve(256 * 4);
  float* bp3   = (float*)carve(128 * 4);
  ushort* bufH        = (ushort*)carve((size_t)NN * 256 * 2);        // bf16: h1, h2 (+ CSR scratch)
  unsigned char* bufZ = (unsigned char*)carve((size_t)NN * 256);     // fp8: z1, z2
  unsigned char* bufZ3 = (unsigned char*)carve((size_t)NN * 64);     // fp8: z3
  if (off > ws_size) return;

  // bucket scratch aliases bufH (not live until spmm1 writes h1): NE*8 = 25.6MB <= 51.2MB
  int2* bdata = (int2*)bufH;

  hipMemsetAsync(bcnt, 0, (size_t)NBUCK * 4, stream);
  // weight prep | edge histogram
  k_pc<<<1031, 256, 0, stream>>>(W1, b1, g1, be1, m1, v1, W2, b2, g2, be2, m2, v2, W3, b3,
                                 W1t, W2t, W3t, bp1, bp2, bp3, erow, ghist, bcnt);
  // per-bucket offset scan (self-computed bases)
  k_scan3<<<NBUCK, 64, 0, stream>>>(ghist, bcnt, bbase);
  // GEMM1 (z1 = x @ W1' + b1', fp32 in, fp8 out, conflict-free staging) | edge placement
  k_pg1<<<1173, 256, 0, stream>>>(x, W1t, bp1, bufZ, erow, ecol, ew, ghist, bdata);
  // row sort -> rp + packed cw
  k_bsort<<<NBUCK, 256, 0, stream>>>(bcnt, bbase, bdata, cw, rp);

  const int gm = (NN + 127) / 128;
  // h1 = relu(P @ z1)
  k_spmm256<<<NN / 4, 256, 0, stream>>>(rp, cw, bufZ, bufH);
  // layer 2: z2 = h1 @ W2' + b2'
  k_gemm<<<dim3(gm, 2), 256, 0, stream>>>(bufH, W2t, bp2, bufZ, NN, 256, 256);
  // h2 = relu(P @ z2)
  k_spmm256<<<NN / 4, 256, 0, stream>>>(rp, cw, bufZ, bufH);
  // layer 3: z3 = h2 @ W3 + b3
  k_gemm<<<dim3(gm, 1), 256, 0, stream>>>(bufH, W3t, bp3, bufZ3, NN, 64, 64);
  // out = log_softmax(P @ z3)
  k_spmm64<<<NN / 4, 256, 0, stream>>>(rp, cw, bufZ3, (float*)d_out);
}